// Round 7
// baseline (143.224 us; speedup 1.0000x reference)
//
#include <hip/hip_runtime.h>
#include <math.h>

#define Cn 192
#define Bn 8
#define Tn 4096
#define HW 64

typedef unsigned short u16;
typedef unsigned int u32;
typedef __attribute__((ext_vector_type(8))) __bf16 bf16x8;
typedef __attribute__((ext_vector_type(16))) float f32x16;

__device__ __forceinline__ void split_bf16(float x, u16 &h, u16 &l) {
    u32 u = __float_as_uint(x);
    u32 uh = (u + 0x7FFFu + ((u >> 16) & 1u)) & 0xFFFF0000u;
    h = (u16)(uh >> 16);
    float r = x - __uint_as_float(uh);
    u32 ur = __float_as_uint(r);
    l = (u16)((ur + 0x7FFFu + ((ur >> 16) & 1u)) >> 16);
}

// ---------------------------------------------------------------------------
// Kernel 1: omni_shift (fused 25-tap depthwise conv) -> split bf16 hi/lo out.
// Blocks >= 1536 perform the weight hi/lo split (fused to save a dispatch).
// ---------------------------------------------------------------------------
__global__ __launch_bounds__(256) void omni_kernel(const float* __restrict__ x,
                                                   const float* __restrict__ alpha,
                                                   const float* __restrict__ dw1,
                                                   const float* __restrict__ dw3,
                                                   const float* __restrict__ dw5,
                                                   const float* __restrict__ Wk,
                                                   const float* __restrict__ Wv,
                                                   const float* __restrict__ Wr,
                                                   const float* __restrict__ Wo,
                                                   u16* __restrict__ xhi,
                                                   u16* __restrict__ xlo,
                                                   u16* __restrict__ wh,
                                                   u16* __restrict__ wl) {
    const int tid = threadIdx.x;
    if (blockIdx.x >= 1536) {
        const int base = (blockIdx.x - 1536) * 768;
        #pragma unroll
        for (int jj = 0; jj < 3; ++jj) {
            int idx = base + jj * 256 + tid;
            int mat = idx / 36864;
            int off = idx - mat * 36864;
            const float* src = (mat == 0) ? Wk : (mat == 1) ? Wv : (mat == 2) ? Wr : Wo;
            u16 h, l;
            split_bf16(src[off], h, l);
            wh[idx] = h;
            wl[idx] = l;
        }
        return;
    }

    const int plane = blockIdx.x;          // b*C + c
    const int c = plane % Cn;
    const float* xin = x + (size_t)plane * Tn;
    u16* oh = xhi + (size_t)plane * Tn;
    u16* ol = xlo + (size_t)plane * Tn;

    __shared__ float tile[68 * 68];
    __shared__ float wk[25];

    if (tid == 0) {
        const float a0 = alpha[0], a1 = alpha[1], a2 = alpha[2], a3 = alpha[3];
        #pragma unroll
        for (int j = 0; j < 25; ++j) wk[j] = a3 * dw5[c * 25 + j];
        #pragma unroll
        for (int dy = 0; dy < 3; ++dy)
            #pragma unroll
            for (int dx = 0; dx < 3; ++dx)
                wk[(dy + 1) * 5 + (dx + 1)] += a2 * dw3[c * 9 + dy * 3 + dx];
        wk[12] += a1 * dw1[c] + a0;
    }
    for (int i = tid; i < 68 * 68; i += 256) {
        int r = i / 68, cc = i - r * 68;
        int gy = r - 2, gx = cc - 2;
        float v = 0.f;
        if (gy >= 0 && gy < HW && gx >= 0 && gx < HW) v = xin[gy * HW + gx];
        tile[i] = v;
    }
    __syncthreads();

    const int py = tid >> 3;          // 0..31
    const int px0 = (tid & 7) << 3;   // 0,8,..,56

    #pragma unroll
    for (int half = 0; half < 2; ++half) {
        const int y = py + half * 32;
        float row[5][12];
        #pragma unroll
        for (int dy = 0; dy < 5; ++dy) {
            const float4* rp = (const float4*)&tile[(y + dy) * 68 + px0];
            float4 r0 = rp[0], r1 = rp[1], r2 = rp[2];
            row[dy][0] = r0.x; row[dy][1] = r0.y; row[dy][2]  = r0.z; row[dy][3]  = r0.w;
            row[dy][4] = r1.x; row[dy][5] = r1.y; row[dy][6]  = r1.z; row[dy][7]  = r1.w;
            row[dy][8] = r2.x; row[dy][9] = r2.y; row[dy][10] = r2.z; row[dy][11] = r2.w;
        }
        u32 ph[4], pl[4];
        #pragma unroll
        for (int jj = 0; jj < 8; ++jj) {
            float acc = 0.f;
            #pragma unroll
            for (int dy = 0; dy < 5; ++dy)
                #pragma unroll
                for (int dx = 0; dx < 5; ++dx)
                    acc = fmaf(row[dy][jj + dx], wk[dy * 5 + dx], acc);
            u16 h, l2;
            split_bf16(acc, h, l2);
            if (jj & 1) { ph[jj >> 1] |= ((u32)h) << 16; pl[jj >> 1] |= ((u32)l2) << 16; }
            else        { ph[jj >> 1] = h;               pl[jj >> 1] = l2; }
        }
        *(uint4*)&oh[y * 64 + px0] = make_uint4(ph[0], ph[1], ph[2], ph[3]);
        *(uint4*)&ol[y * 64 + px0] = make_uint4(pl[0], pl[1], pl[2], pl[3]);
    }
}

// ---------------------------------------------------------------------------
// transpose a 4x4 u16 tile held across a lane quad (lane j = row j, uint2 = 4 cols)
// ---------------------------------------------------------------------------
__device__ __forceinline__ uint2 quad_transpose(uint2 v, int j) {
    unsigned int p0 = (unsigned int)__shfl_xor((int)v.x, 1);
    unsigned int p1 = (unsigned int)__shfl_xor((int)v.y, 1);
    unsigned int g0, g1;
    if ((j & 1) == 0) {
        g0 = (p0 << 16) | (v.x & 0xFFFFu);
        g1 = (p1 << 16) | (v.y & 0xFFFFu);
    } else {
        g0 = (v.x & 0xFFFF0000u) | (p0 >> 16);
        g1 = (v.y & 0xFFFF0000u) | (p1 >> 16);
    }
    unsigned int s0 = (unsigned int)__shfl_xor((int)g0, 2);
    unsigned int s1 = (unsigned int)__shfl_xor((int)g1, 2);
    uint2 f;
    if ((j & 2) == 0) { f.x = g0; f.y = s0; }
    else              { f.x = s1; f.y = g1; }
    return f;
}

// ---------------------------------------------------------------------------
// Kernel 2: split-bf16 MFMA GEMM reading X directly from [b][c][t] layout.
// A (weights) lives in REGISTERS (L2-hot, loaded one K-step ahead).
// B tile (32c x 128t) is reg-staged with quad_transpose into a double-buffered
// LDS [t][c] tile (80-B row stride + XOR swizzle -> <=2-way banks both sides).
// One raw s_barrier per K-step; no vmcnt(0) drains (T3/T4 pattern): global
// loads issued one iteration ahead stay in flight across the barrier.
// Out_m[b][row][t] = sum_c W[wrow0 + m*192 + m0 + row][c] * X[b][c][t]
// ---------------------------------------------------------------------------
template<int NM>
__global__ __launch_bounds__(256) void gemm_fused(const u16* __restrict__ wh,
                                                  const u16* __restrict__ wl,
                                                  const u16* __restrict__ Xh,
                                                  const u16* __restrict__ Xl,
                                                  float* __restrict__ O0,
                                                  float* __restrict__ O1,
                                                  float* __restrict__ O2,
                                                  int wrow0) {
    __shared__ u16 B_[2][2][128 * 40];    // [buf][hi/lo][t*40], 80-B rows

    const int tid  = threadIdx.x;
    const int l    = tid & 63;
    const int wave = tid >> 6;
    const int wm   = wave >> 1, wn = wave & 1;
    const int m0   = blockIdx.y * 64;
    const int t0   = blockIdx.x * 128;
    const size_t xb = (size_t)blockIdx.z * Cn * Tn;
    const int j    = tid & 3;

    f32x16 acc[NM][2];
    #pragma unroll
    for (int m = 0; m < NM; ++m)
        #pragma unroll
        for (int nf = 0; nf < 2; ++nf)
            #pragma unroll
            for (int r = 0; r < 16; ++r) acc[m][nf][r] = 0.f;

    uint2 rbh[4], rbl[4];                 // B reg-stage (one K-step)
    bf16x8 rah[NM][2], ral[NM][2];        // A fragments (one K-step)

    auto loadB = [&](int k0) {
        #pragma unroll
        for (int p = 0; p < 4; ++p) {
            int cq = 2 * p + (wave >> 1);
            int tq = ((wave & 1) << 4) + (l >> 2);
            size_t g = xb + (size_t)(k0 + cq * 4 + j) * Tn + t0 + tq * 4;
            rbh[p] = *(const uint2*)&Xh[g];
            rbl[p] = *(const uint2*)&Xl[g];
        }
    };
    auto writeB = [&](int bf) {
        u16* Bh = &B_[bf][0][0];
        u16* Bl = &B_[bf][1][0];
        #pragma unroll
        for (int p = 0; p < 4; ++p) {
            int cq = 2 * p + (wave >> 1);
            int tq = ((wave & 1) << 4) + (l >> 2);
            uint2 th = quad_transpose(rbh[p], j);
            uint2 tl = quad_transpose(rbl[p], j);
            int t = tq * 4 + j;
            int blk = ((cq >> 1) ^ (t >> 1) ^ (t >> 3)) & 3;
            int off = t * 40 + (blk << 3) + ((cq & 1) << 2);
            *(uint2*)&Bh[off] = th;
            *(uint2*)&Bl[off] = tl;
        }
    };
    auto loadA = [&](int k0) {
        #pragma unroll
        for (int m = 0; m < NM; ++m)
            #pragma unroll
            for (int kh = 0; kh < 2; ++kh) {
                int cbb = kh * 2 + (l >> 5);
                int r = wrow0 + m * 192 + m0 + wm * 32 + (l & 31);
                size_t g = (size_t)r * Cn + k0 + cbb * 8;
                rah[m][kh] = *(const bf16x8*)&wh[g];
                ral[m][kh] = *(const bf16x8*)&wl[g];
            }
    };
    auto compute = [&](int bf) {
        const u16* Bh = &B_[bf][0][0];
        const u16* Bl = &B_[bf][1][0];
        #pragma unroll
        for (int kh = 0; kh < 2; ++kh) {
            const int cbb = kh * 2 + (l >> 5);
            #pragma unroll
            for (int nf = 0; nf < 2; ++nf) {
                int t = wn * 64 + nf * 32 + (l & 31);
                int off = t * 40 + (((cbb ^ (t >> 1) ^ (t >> 3)) & 3) << 3);
                bf16x8 bh = *(const bf16x8*)&Bh[off];
                bf16x8 bl = *(const bf16x8*)&Bl[off];
                #pragma unroll
                for (int m = 0; m < NM; ++m) {
                    acc[m][nf] = __builtin_amdgcn_mfma_f32_32x32x16_bf16(rah[m][kh], bh, acc[m][nf], 0, 0, 0);
                    acc[m][nf] = __builtin_amdgcn_mfma_f32_32x32x16_bf16(rah[m][kh], bl, acc[m][nf], 0, 0, 0);
                    acc[m][nf] = __builtin_amdgcn_mfma_f32_32x32x16_bf16(ral[m][kh], bh, acc[m][nf], 0, 0, 0);
                }
            }
        }
    };

    // ---- prologue ----
    loadB(0);
    loadA(0);
    writeB(0);                 // compiler waits vmcnt for rb regs
    loadB(32);                 // B(1) in flight across the barrier
    asm volatile("s_waitcnt lgkmcnt(0)" ::: "memory");
    __builtin_amdgcn_sched_barrier(0);
    __builtin_amdgcn_s_barrier();

    // ---- K loop: one raw barrier per step, loads always in flight ----
    #pragma unroll
    for (int ks = 0; ks < 6; ++ks) {
        __builtin_amdgcn_s_setprio(1);
        compute(ks & 1);
        __builtin_amdgcn_s_setprio(0);
        if (ks < 5) {
            writeB((ks + 1) & 1);          // waits rb = B(ks+1) (issued 1 iter ago)
            asm volatile("s_waitcnt lgkmcnt(0)" ::: "memory");
            __builtin_amdgcn_sched_barrier(0);
            __builtin_amdgcn_s_barrier();
            if (ks < 4) loadB((ks + 2) * 32);
            loadA((ks + 1) * 32);
        }
    }

    // ---- epilogue ----
    float* Os[3] = {O0, O1, O2};
    #pragma unroll
    for (int m = 0; m < NM; ++m) {
        float* O = Os[m] + (size_t)blockIdx.z * Cn * Tn;
        #pragma unroll
        for (int nf = 0; nf < 2; ++nf) {
            int col = t0 + wn * 64 + nf * 32 + (l & 31);
            #pragma unroll
            for (int r = 0; r < 16; ++r) {
                int row = m0 + wm * 32 + (r & 3) + 8 * (r >> 2) + 4 * (l >> 5);
                O[(size_t)row * Tn + col] = acc[m][nf][r];
            }
        }
    }
}

// ---------------------------------------------------------------------------
// Kernel 3: bidirectional WKV + sigmoid(receptance); outputs split bf16 hi/lo.
// ---------------------------------------------------------------------------
__global__ __launch_bounds__(256) void wkv_kernel(const float* __restrict__ kg,
                                                  const float* __restrict__ vg,
                                                  const float* __restrict__ srlg,
                                                  const float* __restrict__ decay,
                                                  const float* __restrict__ boost,
                                                  u16* __restrict__ yhi,
                                                  u16* __restrict__ ylo) {
    const int row = blockIdx.x;       // b*C + d
    const int d = row % Cn;
    const float* kr = kg + (size_t)row * Tn;
    const float* vr = vg + (size_t)row * Tn;
    const float* sr = srlg + (size_t)row * Tn;
    u16* yh = yhi + (size_t)row * Tn;
    u16* yl = ylo + (size_t)row * Tn;

    const int tid = threadIdx.x;
    const int t0 = tid * 16;

    float kk[16], vv[16];
    #pragma unroll
    for (int j = 0; j < 16; j += 4) {
        *(float4*)&kk[j] = *(const float4*)&kr[t0 + j];
        *(float4*)&vv[j] = *(const float4*)&vr[t0 + j];
    }

    __shared__ float red[256];
    float lm = kk[0];
    #pragma unroll
    for (int j = 1; j < 16; ++j) lm = fmaxf(lm, kk[j]);
    red[tid] = lm;
    __syncthreads();
    for (int s = 128; s > 0; s >>= 1) {
        if (tid < s) red[tid] = fmaxf(red[tid], red[tid + s]);
        __syncthreads();
    }
    const float m = red[0];
    __syncthreads();

    const float ww = decay[d] * (1.0f / (float)Tn);
    const float u = boost[d] * (1.0f / (float)Tn);
    const float lam = expf(-ww);
    const float lam16 = expf(-16.0f * ww);

    float a[16];
    #pragma unroll
    for (int j = 0; j < 16; ++j) a[j] = expf(kk[j] - m);

    float SN = 0.f, SD = 0.f;
    #pragma unroll
    for (int j = 0; j < 16; ++j) { SN = fmaf(lam, SN, a[j] * vv[j]); SD = fmaf(lam, SD, a[j]); }
    float BN = 0.f, BD = 0.f;
    #pragma unroll
    for (int j = 15; j >= 0; --j) { BN = fmaf(lam, BN, a[j] * vv[j]); BD = fmaf(lam, BD, a[j]); }

    __shared__ float sN[2][256], sD[2][256];

    sN[0][tid] = SN; sD[0][tid] = SD;
    __syncthreads();
    int src = 0;
    float f = lam16;
    for (int o = 1; o < 256; o <<= 1) {
        float nN = sN[src][tid], nD = sD[src][tid];
        if (tid >= o) { nN = fmaf(f, sN[src][tid - o], nN); nD = fmaf(f, sD[src][tid - o], nD); }
        sN[src ^ 1][tid] = nN; sD[src ^ 1][tid] = nD;
        __syncthreads();
        src ^= 1; f = f * f;
    }
    const float CfN = (tid > 0) ? sN[src][tid - 1] : 0.f;
    const float CfD = (tid > 0) ? sD[src][tid - 1] : 0.f;
    __syncthreads();

    sN[0][tid] = BN; sD[0][tid] = BD;
    __syncthreads();
    src = 0; f = lam16;
    for (int o = 1; o < 256; o <<= 1) {
        float nN = sN[src][tid], nD = sD[src][tid];
        if (tid + o < 256) { nN = fmaf(f, sN[src][tid + o], nN); nD = fmaf(f, sD[src][tid + o], nD); }
        sN[src ^ 1][tid] = nN; sD[src ^ 1][tid] = nD;
        __syncthreads();
        src ^= 1; f = f * f;
    }
    const float CbN = (tid < 255) ? sN[src][tid + 1] : 0.f;
    const float CbD = (tid < 255) ? sD[src][tid + 1] : 0.f;

    float fN[16], fD[16];
    float cN = CfN, cD = CfD;
    #pragma unroll
    for (int j = 0; j < 16; ++j) {
        fN[j] = cN; fD[j] = cD;
        cN = fmaf(lam, cN, a[j] * vv[j]);
        cD = fmaf(lam, cD, a[j]);
    }

    float sl[16];
    #pragma unroll
    for (int j = 0; j < 16; j += 4) *(float4*)&sl[j] = *(const float4*)&sr[t0 + j];

    u16 oh[16], ol[16];
    float bN = CbN, bD = CbD;
    #pragma unroll
    for (int j = 15; j >= 0; --j) {
        const float es = expf(u + kk[j] - m);
        const float num = fN[j] + bN + es * vv[j];
        const float den = fD[j] + bD + es;
        const float y = num / den;
        const float sig = 1.0f / (1.0f + expf(-sl[j]));
        split_bf16(sig * y, oh[j], ol[j]);
        bN = fmaf(lam, bN, a[j] * vv[j]);
        bD = fmaf(lam, bD, a[j]);
    }

    u32 ph[8], pl[8];
    #pragma unroll
    for (int j = 0; j < 8; ++j) {
        ph[j] = (u32)oh[2 * j] | ((u32)oh[2 * j + 1] << 16);
        pl[j] = (u32)ol[2 * j] | ((u32)ol[2 * j + 1] << 16);
    }
    *(uint4*)&yh[t0]     = make_uint4(ph[0], ph[1], ph[2], ph[3]);
    *(uint4*)&yh[t0 + 8] = make_uint4(ph[4], ph[5], ph[6], ph[7]);
    *(uint4*)&yl[t0]     = make_uint4(pl[0], pl[1], pl[2], pl[3]);
    *(uint4*)&yl[t0 + 8] = make_uint4(pl[4], pl[5], pl[6], pl[7]);
}

// ---------------------------------------------------------------------------
extern "C" void kernel_launch(void* const* d_in, const int* in_sizes, int n_in,
                              void* d_out, int out_size, void* d_ws, size_t ws_size,
                              hipStream_t stream) {
    const float* x        = (const float*)d_in[0];
    const float* w_key    = (const float*)d_in[1];
    const float* w_value  = (const float*)d_in[2];
    const float* w_recept = (const float*)d_in[3];
    const float* w_out    = (const float*)d_in[4];
    const float* decay    = (const float*)d_in[5];
    const float* boost    = (const float*)d_in[6];
    const float* alpha    = (const float*)d_in[7];
    const float* dw1      = (const float*)d_in[8];
    const float* dw3      = (const float*)d_in[9];
    const float* dw5      = (const float*)d_in[10];

    const size_t S = (size_t)Bn * Cn * Tn;   // 6291456 elements
    u16* R0 = (u16*)d_ws;                    // 2S u16 each region
    u16* R1 = R0 + 2 * S;
    u16* R2 = R1 + 2 * S;
    u16* whp = R2 + 2 * S;                   // stacked weights hi (4*36864)
    u16* wlp = whp + 4 * 36864;

    u16* xs_hi = R0;        u16* xs_lo = R0 + S;      // omni out / proj in
    float* kb  = (float*)R1;                          // proj out
    float* vb  = (float*)R2;
    float* srl = (float*)d_out;                       // scratch until final GEMM
    u16* y_hi  = R0;        u16* y_lo  = R0 + S;      // wkv out (xs dead)
    float* out = (float*)d_out;

    // blocks 1536..1727 also perform the weight hi/lo split
    omni_kernel<<<dim3(1536 + 192), 256, 0, stream>>>(x, alpha, dw1, dw3, dw5,
                                                      w_key, w_value, w_recept, w_out,
                                                      xs_hi, xs_lo, whp, wlp);

    gemm_fused<3><<<dim3(32, 3, 8), 256, 0, stream>>>(whp, wlp, xs_hi, xs_lo, kb, vb, srl, 0);

    wkv_kernel<<<dim3(Bn * Cn), 256, 0, stream>>>(kb, vb, srl, decay, boost, y_hi, y_lo);

    gemm_fused<1><<<dim3(32, 3, 8), 256, 0, stream>>>(whp, wlp, y_hi, y_lo, out, nullptr, nullptr, 576);
}

// Round 8
// 128.373 us; speedup vs baseline: 1.1157x; 1.1157x over previous
//
#include <hip/hip_runtime.h>
#include <math.h>

#define Cn 192
#define Bn 8
#define Tn 4096
#define HW 64

typedef unsigned short u16;
typedef unsigned int u32;
typedef __attribute__((ext_vector_type(8))) __bf16 bf16x8;
typedef __attribute__((ext_vector_type(16))) float f32x16;

__device__ __forceinline__ void split_bf16(float x, u16 &h, u16 &l) {
    u32 u = __float_as_uint(x);
    u32 uh = (u + 0x7FFFu + ((u >> 16) & 1u)) & 0xFFFF0000u;
    h = (u16)(uh >> 16);
    float r = x - __uint_as_float(uh);
    u32 ur = __float_as_uint(r);
    l = (u16)((ur + 0x7FFFu + ((ur >> 16) & 1u)) >> 16);
}

// ---------------------------------------------------------------------------
// Kernel 1: omni_shift (fused 25-tap depthwise conv) -> split bf16 hi/lo out.
// Blocks >= 1536 perform the weight hi/lo split (fused to save a dispatch).
// ---------------------------------------------------------------------------
__global__ __launch_bounds__(256) void omni_kernel(const float* __restrict__ x,
                                                   const float* __restrict__ alpha,
                                                   const float* __restrict__ dw1,
                                                   const float* __restrict__ dw3,
                                                   const float* __restrict__ dw5,
                                                   const float* __restrict__ Wk,
                                                   const float* __restrict__ Wv,
                                                   const float* __restrict__ Wr,
                                                   const float* __restrict__ Wo,
                                                   u16* __restrict__ xhi,
                                                   u16* __restrict__ xlo,
                                                   u16* __restrict__ wh,
                                                   u16* __restrict__ wl) {
    const int tid = threadIdx.x;
    if (blockIdx.x >= 1536) {
        const int base = (blockIdx.x - 1536) * 768;
        #pragma unroll
        for (int jj = 0; jj < 3; ++jj) {
            int idx = base + jj * 256 + tid;
            int mat = idx / 36864;
            int off = idx - mat * 36864;
            const float* src = (mat == 0) ? Wk : (mat == 1) ? Wv : (mat == 2) ? Wr : Wo;
            u16 h, l;
            split_bf16(src[off], h, l);
            wh[idx] = h;
            wl[idx] = l;
        }
        return;
    }

    const int plane = blockIdx.x;          // b*C + c
    const int c = plane % Cn;
    const float* xin = x + (size_t)plane * Tn;
    u16* oh = xhi + (size_t)plane * Tn;
    u16* ol = xlo + (size_t)plane * Tn;

    __shared__ float tile[68 * 68];
    __shared__ float wk[25];

    if (tid == 0) {
        const float a0 = alpha[0], a1 = alpha[1], a2 = alpha[2], a3 = alpha[3];
        #pragma unroll
        for (int j = 0; j < 25; ++j) wk[j] = a3 * dw5[c * 25 + j];
        #pragma unroll
        for (int dy = 0; dy < 3; ++dy)
            #pragma unroll
            for (int dx = 0; dx < 3; ++dx)
                wk[(dy + 1) * 5 + (dx + 1)] += a2 * dw3[c * 9 + dy * 3 + dx];
        wk[12] += a1 * dw1[c] + a0;
    }
    for (int i = tid; i < 68 * 68; i += 256) {
        int r = i / 68, cc = i - r * 68;
        int gy = r - 2, gx = cc - 2;
        float v = 0.f;
        if (gy >= 0 && gy < HW && gx >= 0 && gx < HW) v = xin[gy * HW + gx];
        tile[i] = v;
    }
    __syncthreads();

    const int py = tid >> 3;          // 0..31
    const int px0 = (tid & 7) << 3;   // 0,8,..,56

    #pragma unroll
    for (int half = 0; half < 2; ++half) {
        const int y = py + half * 32;
        float row[5][12];
        #pragma unroll
        for (int dy = 0; dy < 5; ++dy) {
            const float4* rp = (const float4*)&tile[(y + dy) * 68 + px0];
            float4 r0 = rp[0], r1 = rp[1], r2 = rp[2];
            row[dy][0] = r0.x; row[dy][1] = r0.y; row[dy][2]  = r0.z; row[dy][3]  = r0.w;
            row[dy][4] = r1.x; row[dy][5] = r1.y; row[dy][6]  = r1.z; row[dy][7]  = r1.w;
            row[dy][8] = r2.x; row[dy][9] = r2.y; row[dy][10] = r2.z; row[dy][11] = r2.w;
        }
        u32 ph[4], pl[4];
        #pragma unroll
        for (int jj = 0; jj < 8; ++jj) {
            float acc = 0.f;
            #pragma unroll
            for (int dy = 0; dy < 5; ++dy)
                #pragma unroll
                for (int dx = 0; dx < 5; ++dx)
                    acc = fmaf(row[dy][jj + dx], wk[dy * 5 + dx], acc);
            u16 h, l2;
            split_bf16(acc, h, l2);
            if (jj & 1) { ph[jj >> 1] |= ((u32)h) << 16; pl[jj >> 1] |= ((u32)l2) << 16; }
            else        { ph[jj >> 1] = h;               pl[jj >> 1] = l2; }
        }
        *(uint4*)&oh[y * 64 + px0] = make_uint4(ph[0], ph[1], ph[2], ph[3]);
        *(uint4*)&ol[y * 64 + px0] = make_uint4(pl[0], pl[1], pl[2], pl[3]);
    }
}

// ---------------------------------------------------------------------------
// transpose a 4x4 u16 tile held across a lane quad (lane j = row j, uint2 = 4 cols)
// ---------------------------------------------------------------------------
__device__ __forceinline__ uint2 quad_transpose(uint2 v, int j) {
    unsigned int p0 = (unsigned int)__shfl_xor((int)v.x, 1);
    unsigned int p1 = (unsigned int)__shfl_xor((int)v.y, 1);
    unsigned int g0, g1;
    if ((j & 1) == 0) {
        g0 = (p0 << 16) | (v.x & 0xFFFFu);
        g1 = (p1 << 16) | (v.y & 0xFFFFu);
    } else {
        g0 = (v.x & 0xFFFF0000u) | (p0 >> 16);
        g1 = (v.y & 0xFFFF0000u) | (p1 >> 16);
    }
    unsigned int s0 = (unsigned int)__shfl_xor((int)g0, 2);
    unsigned int s1 = (unsigned int)__shfl_xor((int)g1, 2);
    uint2 f;
    if ((j & 2) == 0) { f.x = g0; f.y = s0; }
    else              { f.x = s1; f.y = g1; }
    return f;
}

// ---------------------------------------------------------------------------
// Kernel 2: split-bf16 MFMA GEMM reading X directly from [b][c][t] layout.
// Both operands reg-staged COALESCED (A: 4 lanes/row x 16B; B: quad-transposed
// dwordx4), single-buffered LDS with zero-pad XOR swizzle
//   slot(r,cb) = cb ^ (((r>>1)^(r>>3))&3)   (conflict-free b128 reads,
//   floor-rate b64/b128 writes by bank arithmetic).
// Two raw s_barriers per K-step (readers-done / writes-visible); global loads
// issued one full K-step ahead and never drained by vmcnt(0).
// Out_m[b][row][t] = sum_c W[wrow0 + m*192 + m0 + row][c] * X[b][c][t]
// ---------------------------------------------------------------------------
template<int NM>
__global__ __launch_bounds__(256) void gemm_fused(const u16* __restrict__ wh,
                                                  const u16* __restrict__ wl,
                                                  const u16* __restrict__ Xh,
                                                  const u16* __restrict__ Xl,
                                                  float* __restrict__ O0,
                                                  float* __restrict__ O1,
                                                  float* __restrict__ O2,
                                                  int wrow0) {
    constexpr int ARows = NM * 64;
    __shared__ __align__(16) u16 Ah_[ARows * 32];
    __shared__ __align__(16) u16 Al_[ARows * 32];
    __shared__ __align__(16) u16 Bh_[128 * 32];
    __shared__ __align__(16) u16 Bl_[128 * 32];

    const int tid  = threadIdx.x;
    const int l    = tid & 63;
    const int wave = tid >> 6;
    const int wm   = wave >> 1, wn = wave & 1;
    const int m0   = blockIdx.y * 64;
    const int t0   = blockIdx.x * 128;
    const size_t xb = (size_t)blockIdx.z * Cn * Tn;
    const int j    = tid & 3;
    const int q    = tid >> 2;

    f32x16 acc[NM][2];
    #pragma unroll
    for (int m = 0; m < NM; ++m)
        #pragma unroll
        for (int nf = 0; nf < 2; ++nf)
            #pragma unroll
            for (int r = 0; r < 16; ++r) acc[m][nf][r] = 0.f;

    uint4 rAh[NM], rAl[NM];      // A reg-stage (one K-step)
    uint4 rBh[2], rBl[2];        // B reg-stage (one K-step)

    auto offSw = [](int r, int cb) {
        return (r * 4 + (cb ^ (((r >> 1) ^ (r >> 3)) & 3))) * 8;   // u16 units
    };

    auto loadA = [&](int k0) {
        #pragma unroll
        for (int i = 0; i < NM; ++i) {
            int idx = i * 256 + tid;
            int r = idx >> 2;                            // 4 lanes per row
            int grow = wrow0 + (r >> 6) * 192 + m0 + (r & 63);
            size_t g = (size_t)grow * Cn + k0 + j * 8;   // 64B dense per row
            rAh[i] = *(const uint4*)&wh[g];
            rAl[i] = *(const uint4*)&wl[g];
        }
    };
    auto writeA = [&]() {
        #pragma unroll
        for (int i = 0; i < NM; ++i) {
            int idx = i * 256 + tid;
            int r = idx >> 2;
            int off = offSw(r, j);
            *(uint4*)&Ah_[off] = rAh[i];
            *(uint4*)&Al_[off] = rAl[i];
        }
    };
    auto loadB = [&](int k0) {
        #pragma unroll
        for (int p = 0; p < 2; ++p) {
            int cq = (q >> 4) + 4 * p;                   // c-quad 0..7
            int toct = q & 15;                           // t-oct
            size_t g = xb + (size_t)(k0 + cq * 4 + j) * Tn + t0 + toct * 8;
            rBh[p] = *(const uint4*)&Xh[g];
            rBl[p] = *(const uint4*)&Xl[g];
        }
    };
    auto writeB = [&]() {
        #pragma unroll
        for (int p = 0; p < 2; ++p) {
            int cq = (q >> 4) + 4 * p;
            int toct = q & 15;
            int cb = cq >> 1, hf = (cq & 1) * 4;
            uint2 va, vb2, la, lb;
            va.x = rBh[p].x; va.y = rBh[p].y;
            vb2.x = rBh[p].z; vb2.y = rBh[p].w;
            la.x = rBl[p].x; la.y = rBl[p].y;
            lb.x = rBl[p].z; lb.y = rBl[p].w;
            uint2 ha = quad_transpose(va, j);
            uint2 hb = quad_transpose(vb2, j);
            uint2 ja_ = quad_transpose(la, j);
            uint2 jb_ = quad_transpose(lb, j);
            int t_a = toct * 8 + j;
            int t_b = toct * 8 + 4 + j;
            *(uint2*)&Bh_[offSw(t_a, cb) + hf] = ha;
            *(uint2*)&Bh_[offSw(t_b, cb) + hf] = hb;
            *(uint2*)&Bl_[offSw(t_a, cb) + hf] = ja_;
            *(uint2*)&Bl_[offSw(t_b, cb) + hf] = jb_;
        }
    };
    auto compute = [&]() {
        #pragma unroll
        for (int kh = 0; kh < 2; ++kh) {
            const int cbb = kh * 2 + (l >> 5);
            bf16x8 ah[NM], al[NM];
            #pragma unroll
            for (int m = 0; m < NM; ++m) {
                int r = m * 64 + wm * 32 + (l & 31);
                ah[m] = *(const bf16x8*)&Ah_[offSw(r, cbb)];
                al[m] = *(const bf16x8*)&Al_[offSw(r, cbb)];
            }
            #pragma unroll
            for (int nf = 0; nf < 2; ++nf) {
                int t = wn * 64 + nf * 32 + (l & 31);
                bf16x8 bh = *(const bf16x8*)&Bh_[offSw(t, cbb)];
                bf16x8 bl = *(const bf16x8*)&Bl_[offSw(t, cbb)];
                #pragma unroll
                for (int m = 0; m < NM; ++m) {
                    acc[m][nf] = __builtin_amdgcn_mfma_f32_32x32x16_bf16(ah[m], bh, acc[m][nf], 0, 0, 0);
                    acc[m][nf] = __builtin_amdgcn_mfma_f32_32x32x16_bf16(ah[m], bl, acc[m][nf], 0, 0, 0);
                    acc[m][nf] = __builtin_amdgcn_mfma_f32_32x32x16_bf16(al[m], bh, acc[m][nf], 0, 0, 0);
                }
            }
        }
    };

    // ---- prologue ----
    loadA(0); loadB(0);
    writeA(); writeB();                     // compiler waits vmcnt for regs
    asm volatile("s_waitcnt lgkmcnt(0)" ::: "memory");
    __builtin_amdgcn_sched_barrier(0);
    __builtin_amdgcn_s_barrier();
    __builtin_amdgcn_sched_barrier(0);
    loadA(32); loadB(32);                   // next K-step in flight

    // ---- K loop: 2 raw barriers per step, loads always in flight ----
    #pragma unroll
    for (int ks = 0; ks < 6; ++ks) {
        __builtin_amdgcn_s_setprio(1);
        compute();
        __builtin_amdgcn_s_setprio(0);
        if (ks < 5) {
            __builtin_amdgcn_sched_barrier(0);
            __builtin_amdgcn_s_barrier();   // bar1: all waves done reading LDS
            writeA(); writeB();             // waits vmcnt (issued 1 step ago)
            asm volatile("s_waitcnt lgkmcnt(0)" ::: "memory");
            __builtin_amdgcn_sched_barrier(0);
            __builtin_amdgcn_s_barrier();   // bar2: writes visible
            __builtin_amdgcn_sched_barrier(0);
            if (ks < 4) { loadA((ks + 2) * 32); loadB((ks + 2) * 32); }
        }
    }

    // ---- epilogue ----
    float* Os[3] = {O0, O1, O2};
    #pragma unroll
    for (int m = 0; m < NM; ++m) {
        float* O = Os[m] + (size_t)blockIdx.z * Cn * Tn;
        #pragma unroll
        for (int nf = 0; nf < 2; ++nf) {
            int col = t0 + wn * 64 + nf * 32 + (l & 31);
            #pragma unroll
            for (int r = 0; r < 16; ++r) {
                int row = m0 + wm * 32 + (r & 3) + 8 * (r >> 2) + 4 * (l >> 5);
                O[(size_t)row * Tn + col] = acc[m][nf][r];
            }
        }
    }
}

// ---------------------------------------------------------------------------
// Kernel 3: bidirectional WKV + sigmoid(receptance); outputs split bf16 hi/lo.
// ---------------------------------------------------------------------------
__global__ __launch_bounds__(256) void wkv_kernel(const float* __restrict__ kg,
                                                  const float* __restrict__ vg,
                                                  const float* __restrict__ srlg,
                                                  const float* __restrict__ decay,
                                                  const float* __restrict__ boost,
                                                  u16* __restrict__ yhi,
                                                  u16* __restrict__ ylo) {
    const int row = blockIdx.x;       // b*C + d
    const int d = row % Cn;
    const float* kr = kg + (size_t)row * Tn;
    const float* vr = vg + (size_t)row * Tn;
    const float* sr = srlg + (size_t)row * Tn;
    u16* yh = yhi + (size_t)row * Tn;
    u16* yl = ylo + (size_t)row * Tn;

    const int tid = threadIdx.x;
    const int t0 = tid * 16;

    float kk[16], vv[16];
    #pragma unroll
    for (int j = 0; j < 16; j += 4) {
        *(float4*)&kk[j] = *(const float4*)&kr[t0 + j];
        *(float4*)&vv[j] = *(const float4*)&vr[t0 + j];
    }

    __shared__ float red[256];
    float lm = kk[0];
    #pragma unroll
    for (int j = 1; j < 16; ++j) lm = fmaxf(lm, kk[j]);
    red[tid] = lm;
    __syncthreads();
    for (int s = 128; s > 0; s >>= 1) {
        if (tid < s) red[tid] = fmaxf(red[tid], red[tid + s]);
        __syncthreads();
    }
    const float m = red[0];
    __syncthreads();

    const float ww = decay[d] * (1.0f / (float)Tn);
    const float u = boost[d] * (1.0f / (float)Tn);
    const float lam = expf(-ww);
    const float lam16 = expf(-16.0f * ww);

    float a[16];
    #pragma unroll
    for (int j = 0; j < 16; ++j) a[j] = expf(kk[j] - m);

    float SN = 0.f, SD = 0.f;
    #pragma unroll
    for (int j = 0; j < 16; ++j) { SN = fmaf(lam, SN, a[j] * vv[j]); SD = fmaf(lam, SD, a[j]); }
    float BN = 0.f, BD = 0.f;
    #pragma unroll
    for (int j = 15; j >= 0; --j) { BN = fmaf(lam, BN, a[j] * vv[j]); BD = fmaf(lam, BD, a[j]); }

    __shared__ float sN[2][256], sD[2][256];

    sN[0][tid] = SN; sD[0][tid] = SD;
    __syncthreads();
    int src = 0;
    float f = lam16;
    for (int o = 1; o < 256; o <<= 1) {
        float nN = sN[src][tid], nD = sD[src][tid];
        if (tid >= o) { nN = fmaf(f, sN[src][tid - o], nN); nD = fmaf(f, sD[src][tid - o], nD); }
        sN[src ^ 1][tid] = nN; sD[src ^ 1][tid] = nD;
        __syncthreads();
        src ^= 1; f = f * f;
    }
    const float CfN = (tid > 0) ? sN[src][tid - 1] : 0.f;
    const float CfD = (tid > 0) ? sD[src][tid - 1] : 0.f;
    __syncthreads();

    sN[0][tid] = BN; sD[0][tid] = BD;
    __syncthreads();
    src = 0; f = lam16;
    for (int o = 1; o < 256; o <<= 1) {
        float nN = sN[src][tid], nD = sD[src][tid];
        if (tid + o < 256) { nN = fmaf(f, sN[src][tid + o], nN); nD = fmaf(f, sD[src][tid + o], nD); }
        sN[src ^ 1][tid] = nN; sD[src ^ 1][tid] = nD;
        __syncthreads();
        src ^= 1; f = f * f;
    }
    const float CbN = (tid < 255) ? sN[src][tid + 1] : 0.f;
    const float CbD = (tid < 255) ? sD[src][tid + 1] : 0.f;

    float fN[16], fD[16];
    float cN = CfN, cD = CfD;
    #pragma unroll
    for (int j = 0; j < 16; ++j) {
        fN[j] = cN; fD[j] = cD;
        cN = fmaf(lam, cN, a[j] * vv[j]);
        cD = fmaf(lam, cD, a[j]);
    }

    float sl[16];
    #pragma unroll
    for (int j = 0; j < 16; j += 4) *(float4*)&sl[j] = *(const float4*)&sr[t0 + j];

    u16 oh[16], ol[16];
    float bN = CbN, bD = CbD;
    #pragma unroll
    for (int j = 15; j >= 0; --j) {
        const float es = expf(u + kk[j] - m);
        const float num = fN[j] + bN + es * vv[j];
        const float den = fD[j] + bD + es;
        const float y = num / den;
        const float sig = 1.0f / (1.0f + expf(-sl[j]));
        split_bf16(sig * y, oh[j], ol[j]);
        bN = fmaf(lam, bN, a[j] * vv[j]);
        bD = fmaf(lam, bD, a[j]);
    }

    u32 ph[8], pl[8];
    #pragma unroll
    for (int j = 0; j < 8; ++j) {
        ph[j] = (u32)oh[2 * j] | ((u32)oh[2 * j + 1] << 16);
        pl[j] = (u32)ol[2 * j] | ((u32)ol[2 * j + 1] << 16);
    }
    *(uint4*)&yh[t0]     = make_uint4(ph[0], ph[1], ph[2], ph[3]);
    *(uint4*)&yh[t0 + 8] = make_uint4(ph[4], ph[5], ph[6], ph[7]);
    *(uint4*)&yl[t0]     = make_uint4(pl[0], pl[1], pl[2], pl[3]);
    *(uint4*)&yl[t0 + 8] = make_uint4(pl[4], pl[5], pl[6], pl[7]);
}

// ---------------------------------------------------------------------------
extern "C" void kernel_launch(void* const* d_in, const int* in_sizes, int n_in,
                              void* d_out, int out_size, void* d_ws, size_t ws_size,
                              hipStream_t stream) {
    const float* x        = (const float*)d_in[0];
    const float* w_key    = (const float*)d_in[1];
    const float* w_value  = (const float*)d_in[2];
    const float* w_recept = (const float*)d_in[3];
    const float* w_out    = (const float*)d_in[4];
    const float* decay    = (const float*)d_in[5];
    const float* boost    = (const float*)d_in[6];
    const float* alpha    = (const float*)d_in[7];
    const float* dw1      = (const float*)d_in[8];
    const float* dw3      = (const float*)d_in[9];
    const float* dw5      = (const float*)d_in[10];

    const size_t S = (size_t)Bn * Cn * Tn;   // 6291456 elements
    u16* R0 = (u16*)d_ws;                    // 2S u16 each region
    u16* R1 = R0 + 2 * S;
    u16* R2 = R1 + 2 * S;
    u16* whp = R2 + 2 * S;                   // stacked weights hi (4*36864)
    u16* wlp = whp + 4 * 36864;

    u16* xs_hi = R0;        u16* xs_lo = R0 + S;      // omni out / proj in
    float* kb  = (float*)R1;                          // proj out
    float* vb  = (float*)R2;
    float* srl = (float*)d_out;                       // scratch until final GEMM
    u16* y_hi  = R0;        u16* y_lo  = R0 + S;      // wkv out (xs dead)
    float* out = (float*)d_out;

    // blocks 1536..1727 also perform the weight hi/lo split
    omni_kernel<<<dim3(1536 + 192), 256, 0, stream>>>(x, alpha, dw1, dw3, dw5,
                                                      w_key, w_value, w_recept, w_out,
                                                      xs_hi, xs_lo, whp, wlp);

    gemm_fused<3><<<dim3(32, 3, 8), 256, 0, stream>>>(whp, wlp, xs_hi, xs_lo, kb, vb, srl, 0);

    wkv_kernel<<<dim3(Bn * Cn), 256, 0, stream>>>(kb, vb, srl, decay, boost, y_hi, y_lo);

    gemm_fused<1><<<dim3(32, 3, 8), 256, 0, stream>>>(whp, wlp, y_hi, y_lo, out, nullptr, nullptr, 576);
}

// Round 9
// 121.880 us; speedup vs baseline: 1.1751x; 1.0533x over previous
//
#include <hip/hip_runtime.h>
#include <math.h>

#define Cn 192
#define Bn 8
#define Tn 4096
#define HW 64

typedef unsigned short u16;
typedef unsigned int u32;
typedef __attribute__((ext_vector_type(8))) __bf16 bf16x8;
typedef __attribute__((ext_vector_type(16))) float f32x16;

__device__ __forceinline__ void gload16(const void* g, void* l) {
    __builtin_amdgcn_global_load_lds(
        (const __attribute__((address_space(1))) void*)g,
        (__attribute__((address_space(3))) void*)l, 16, 0, 0);
}

__device__ __forceinline__ void split_bf16(float x, u16 &h, u16 &l) {
    u32 u = __float_as_uint(x);
    u32 uh = (u + 0x7FFFu + ((u >> 16) & 1u)) & 0xFFFF0000u;
    h = (u16)(uh >> 16);
    float r = x - __uint_as_float(uh);
    u32 ur = __float_as_uint(r);
    l = (u16)((ur + 0x7FFFu + ((ur >> 16) & 1u)) >> 16);
}

// ---------------------------------------------------------------------------
// Kernel 1: omni_shift (fused 25-tap depthwise conv) -> split bf16 hi/lo out.
// Blocks >= 1536 perform the weight hi/lo split (fused to save a dispatch).
// ---------------------------------------------------------------------------
__global__ __launch_bounds__(256) void omni_kernel(const float* __restrict__ x,
                                                   const float* __restrict__ alpha,
                                                   const float* __restrict__ dw1,
                                                   const float* __restrict__ dw3,
                                                   const float* __restrict__ dw5,
                                                   const float* __restrict__ Wk,
                                                   const float* __restrict__ Wv,
                                                   const float* __restrict__ Wr,
                                                   const float* __restrict__ Wo,
                                                   u16* __restrict__ xhi,
                                                   u16* __restrict__ xlo,
                                                   u16* __restrict__ wh,
                                                   u16* __restrict__ wl) {
    const int tid = threadIdx.x;
    if (blockIdx.x >= 1536) {
        const int base = (blockIdx.x - 1536) * 768;
        #pragma unroll
        for (int jj = 0; jj < 3; ++jj) {
            int idx = base + jj * 256 + tid;
            int mat = idx / 36864;
            int off = idx - mat * 36864;
            const float* src = (mat == 0) ? Wk : (mat == 1) ? Wv : (mat == 2) ? Wr : Wo;
            u16 h, l;
            split_bf16(src[off], h, l);
            wh[idx] = h;
            wl[idx] = l;
        }
        return;
    }

    const int plane = blockIdx.x;          // b*C + c
    const int c = plane % Cn;
    const float* xin = x + (size_t)plane * Tn;
    u16* oh = xhi + (size_t)plane * Tn;
    u16* ol = xlo + (size_t)plane * Tn;

    __shared__ float tile[68 * 68];
    __shared__ float wk[25];

    if (tid == 0) {
        const float a0 = alpha[0], a1 = alpha[1], a2 = alpha[2], a3 = alpha[3];
        #pragma unroll
        for (int j = 0; j < 25; ++j) wk[j] = a3 * dw5[c * 25 + j];
        #pragma unroll
        for (int dy = 0; dy < 3; ++dy)
            #pragma unroll
            for (int dx = 0; dx < 3; ++dx)
                wk[(dy + 1) * 5 + (dx + 1)] += a2 * dw3[c * 9 + dy * 3 + dx];
        wk[12] += a1 * dw1[c] + a0;
    }
    for (int i = tid; i < 68 * 68; i += 256) {
        int r = i / 68, cc = i - r * 68;
        int gy = r - 2, gx = cc - 2;
        float v = 0.f;
        if (gy >= 0 && gy < HW && gx >= 0 && gx < HW) v = xin[gy * HW + gx];
        tile[i] = v;
    }
    __syncthreads();

    const int py = tid >> 3;          // 0..31
    const int px0 = (tid & 7) << 3;   // 0,8,..,56

    #pragma unroll
    for (int half = 0; half < 2; ++half) {
        const int y = py + half * 32;
        float row[5][12];
        #pragma unroll
        for (int dy = 0; dy < 5; ++dy) {
            const float4* rp = (const float4*)&tile[(y + dy) * 68 + px0];
            float4 r0 = rp[0], r1 = rp[1], r2 = rp[2];
            row[dy][0] = r0.x; row[dy][1] = r0.y; row[dy][2]  = r0.z; row[dy][3]  = r0.w;
            row[dy][4] = r1.x; row[dy][5] = r1.y; row[dy][6]  = r1.z; row[dy][7]  = r1.w;
            row[dy][8] = r2.x; row[dy][9] = r2.y; row[dy][10] = r2.z; row[dy][11] = r2.w;
        }
        u32 ph[4], pl[4];
        #pragma unroll
        for (int jj = 0; jj < 8; ++jj) {
            float acc = 0.f;
            #pragma unroll
            for (int dy = 0; dy < 5; ++dy)
                #pragma unroll
                for (int dx = 0; dx < 5; ++dx)
                    acc = fmaf(row[dy][jj + dx], wk[dy * 5 + dx], acc);
            u16 h, l2;
            split_bf16(acc, h, l2);
            if (jj & 1) { ph[jj >> 1] |= ((u32)h) << 16; pl[jj >> 1] |= ((u32)l2) << 16; }
            else        { ph[jj >> 1] = h;               pl[jj >> 1] = l2; }
        }
        *(uint4*)&oh[y * 64 + px0] = make_uint4(ph[0], ph[1], ph[2], ph[3]);
        *(uint4*)&ol[y * 64 + px0] = make_uint4(pl[0], pl[1], pl[2], pl[3]);
    }
}

// ---------------------------------------------------------------------------
// Kernel 2: transpose [b][192][4096] -> [b][4096][192] for both hi and lo.
// ---------------------------------------------------------------------------
__global__ __launch_bounds__(256) void transpose_kernel(const u16* __restrict__ ih,
                                                        const u16* __restrict__ il,
                                                        u16* __restrict__ oh,
                                                        u16* __restrict__ ol) {
    __shared__ u32 T[2][128][21];
    const int tid = threadIdx.x;
    const size_t ib = (size_t)blockIdx.z * Cn * Tn;
    const int c0 = blockIdx.y * 32, t0 = blockIdx.x * 128;

    {
        const int c2 = tid >> 4;            // 0..15 (c-pair)
        const int tc = (tid & 15) * 8;      // t offset 0..120
        const size_t ge = ib + (size_t)(c0 + 2 * c2) * Tn + t0 + tc;
        uint4 evh = *(const uint4*)&ih[ge];
        uint4 odh = *(const uint4*)&ih[ge + Tn];
        uint4 evl = *(const uint4*)&il[ge];
        uint4 odl = *(const uint4*)&il[ge + Tn];
        const u32 eh4[4] = {evh.x, evh.y, evh.z, evh.w};
        const u32 oh4[4] = {odh.x, odh.y, odh.z, odh.w};
        const u32 el4[4] = {evl.x, evl.y, evl.z, evl.w};
        const u32 ol4[4] = {odl.x, odl.y, odl.z, odl.w};
        #pragma unroll
        for (int q = 0; q < 4; ++q) {
            T[0][tc + 2 * q    ][c2] = (eh4[q] & 0xFFFFu) | (oh4[q] << 16);
            T[0][tc + 2 * q + 1][c2] = (eh4[q] >> 16) | (oh4[q] & 0xFFFF0000u);
            T[1][tc + 2 * q    ][c2] = (el4[q] & 0xFFFFu) | (ol4[q] << 16);
            T[1][tc + 2 * q + 1][c2] = (el4[q] >> 16) | (ol4[q] & 0xFFFF0000u);
        }
    }
    __syncthreads();
    {
        const int t = tid >> 1;
        const int hf = tid & 1;
        u32 wv[8][2];
        #pragma unroll
        for (int q = 0; q < 8; ++q) {
            wv[q][0] = T[0][t][hf * 8 + q];
            wv[q][1] = T[1][t][hf * 8 + q];
        }
        const size_t go = ib + (size_t)(t0 + t) * Cn + c0 + hf * 16;
        *(uint4*)&oh[go]     = make_uint4(wv[0][0], wv[1][0], wv[2][0], wv[3][0]);
        *(uint4*)&oh[go + 8] = make_uint4(wv[4][0], wv[5][0], wv[6][0], wv[7][0]);
        *(uint4*)&ol[go]     = make_uint4(wv[0][1], wv[1][1], wv[2][1], wv[3][1]);
        *(uint4*)&ol[go + 8] = make_uint4(wv[4][1], wv[5][1], wv[6][1], wv[7][1]);
    }
}

// ---------------------------------------------------------------------------
// Kernel 3: split-bf16 MFMA GEMM, global_load_lds staged, SINGLE-buffered
// both operands -> LDS 41 KB (NM=3, 3 blocks/CU) / 32.8 KB (NM=1, 4 blocks/CU).
// Schedule per K-step: compute -> sync -> stage(A,B) -> sync; the stage drain
// is covered by co-resident blocks (TLP).
// Out_m[b][row][t] = sum_c W[wrow0 + m*192 + m0 + row][c] * Xt[b][t][c]
// ---------------------------------------------------------------------------
template<int NM>
__global__ __launch_bounds__(256) void gemm_mfma(const u16* __restrict__ wh,
                                                 const u16* __restrict__ wl,
                                                 const u16* __restrict__ Xh,
                                                 const u16* __restrict__ Xl,
                                                 float* __restrict__ O0,
                                                 float* __restrict__ O1,
                                                 float* __restrict__ O2,
                                                 int wrow0) {
    constexpr int ASZ = NM * 64 * 32;   // u16 per A array (hi or lo)
    constexpr int BSZ = 128 * 32;       // u16 per B array (hi or lo)
    __shared__ u16 Ah_[ASZ], Al_[ASZ];
    __shared__ u16 Bh_[BSZ], Bl_[BSZ];

    const int tid  = threadIdx.x;
    const int l    = tid & 63;
    const int wave = tid >> 6;
    const int wm   = wave >> 1, wn = wave & 1;
    const int m0   = blockIdx.y * 64;
    const int t0   = blockIdx.x * 128;
    const size_t xb = (size_t)blockIdx.z * Cn * Tn;

    f32x16 acc[NM][2];
    #pragma unroll
    for (int m = 0; m < NM; ++m)
        #pragma unroll
        for (int nf = 0; nf < 2; ++nf)
            #pragma unroll
            for (int r = 0; r < 16; ++r) acc[m][nf][r] = 0.f;

    auto stage = [&](int k0) {
        #pragma unroll
        for (int i = 0; i < NM; ++i) {
            int idx = i * 256 + tid;
            int row = idx >> 2;
            int cb  = (idx & 3) ^ ((row >> 1) & 3);
            int grow = wrow0 + (row >> 6) * 192 + m0 + (row & 63);
            int dst = (i * 256 + wave * 64) * 8;
            gload16(wh + (size_t)grow * Cn + k0 + cb * 8, Ah_ + dst);
            gload16(wl + (size_t)grow * Cn + k0 + cb * 8, Al_ + dst);
        }
        #pragma unroll
        for (int i = 0; i < 2; ++i) {
            int idx = i * 256 + tid;
            int tr  = idx >> 2;
            int cb  = (idx & 3) ^ ((tr >> 1) & 3);
            int dst = (i * 256 + wave * 64) * 8;
            gload16(Xh + xb + (size_t)(t0 + tr) * Cn + k0 + cb * 8, Bh_ + dst);
            gload16(Xl + xb + (size_t)(t0 + tr) * Cn + k0 + cb * 8, Bl_ + dst);
        }
    };

    auto compute = [&]() {
        #pragma unroll
        for (int kh = 0; kh < 2; ++kh) {
            const int cbb = kh * 2 + (l >> 5);
            bf16x8 ah[NM], al[NM];
            #pragma unroll
            for (int m = 0; m < NM; ++m) {
                int r = m * 64 + wm * 32 + (l & 31);
                int off = r * 32 + ((cbb ^ ((r >> 1) & 3)) << 3);
                ah[m] = *(const bf16x8*)&Ah_[off];
                al[m] = *(const bf16x8*)&Al_[off];
            }
            #pragma unroll
            for (int nf = 0; nf < 2; ++nf) {
                int tr = wn * 64 + nf * 32 + (l & 31);
                int off = tr * 32 + ((cbb ^ ((tr >> 1) & 3)) << 3);
                bf16x8 bh = *(const bf16x8*)&Bh_[off];
                bf16x8 bl = *(const bf16x8*)&Bl_[off];
                #pragma unroll
                for (int m = 0; m < NM; ++m) {
                    acc[m][nf] = __builtin_amdgcn_mfma_f32_32x32x16_bf16(ah[m], bh, acc[m][nf], 0, 0, 0);
                    acc[m][nf] = __builtin_amdgcn_mfma_f32_32x32x16_bf16(ah[m], bl, acc[m][nf], 0, 0, 0);
                    acc[m][nf] = __builtin_amdgcn_mfma_f32_32x32x16_bf16(al[m], bh, acc[m][nf], 0, 0, 0);
                }
            }
        }
    };

    stage(0);
    __syncthreads();                     // drains gload_lds -> tile 0 ready
    for (int ks = 0; ks < 6; ++ks) {
        compute();
        if (ks < 5) {
            __syncthreads();             // all waves done reading LDS
            stage((ks + 1) * 32);        // overwrite in place
            __syncthreads();             // drains -> tile ks+1 ready
        }
    }

    float* Os[3] = {O0, O1, O2};
    #pragma unroll
    for (int m = 0; m < NM; ++m) {
        float* O = Os[m] + (size_t)blockIdx.z * Cn * Tn;
        #pragma unroll
        for (int nf = 0; nf < 2; ++nf) {
            int col = t0 + wn * 64 + nf * 32 + (l & 31);
            #pragma unroll
            for (int r = 0; r < 16; ++r) {
                int row = m0 + wm * 32 + (r & 3) + 8 * (r >> 2) + 4 * (l >> 5);
                O[(size_t)row * Tn + col] = acc[m][nf][r];
            }
        }
    }
}

// ---------------------------------------------------------------------------
// Kernel 4: bidirectional WKV + sigmoid(receptance); outputs split bf16 hi/lo.
// ---------------------------------------------------------------------------
__global__ __launch_bounds__(256) void wkv_kernel(const float* __restrict__ kg,
                                                  const float* __restrict__ vg,
                                                  const float* __restrict__ srlg,
                                                  const float* __restrict__ decay,
                                                  const float* __restrict__ boost,
                                                  u16* __restrict__ yhi,
                                                  u16* __restrict__ ylo) {
    const int row = blockIdx.x;       // b*C + d
    const int d = row % Cn;
    const float* kr = kg + (size_t)row * Tn;
    const float* vr = vg + (size_t)row * Tn;
    const float* sr = srlg + (size_t)row * Tn;
    u16* yh = yhi + (size_t)row * Tn;
    u16* yl = ylo + (size_t)row * Tn;

    const int tid = threadIdx.x;
    const int t0 = tid * 16;

    float kk[16], vv[16];
    #pragma unroll
    for (int j = 0; j < 16; j += 4) {
        *(float4*)&kk[j] = *(const float4*)&kr[t0 + j];
        *(float4*)&vv[j] = *(const float4*)&vr[t0 + j];
    }

    __shared__ float red[256];
    float lm = kk[0];
    #pragma unroll
    for (int j = 1; j < 16; ++j) lm = fmaxf(lm, kk[j]);
    red[tid] = lm;
    __syncthreads();
    for (int s = 128; s > 0; s >>= 1) {
        if (tid < s) red[tid] = fmaxf(red[tid], red[tid + s]);
        __syncthreads();
    }
    const float m = red[0];
    __syncthreads();

    const float ww = decay[d] * (1.0f / (float)Tn);
    const float u = boost[d] * (1.0f / (float)Tn);
    const float lam = expf(-ww);
    const float lam16 = expf(-16.0f * ww);

    float a[16];
    #pragma unroll
    for (int j = 0; j < 16; ++j) a[j] = expf(kk[j] - m);

    float SN = 0.f, SD = 0.f;
    #pragma unroll
    for (int j = 0; j < 16; ++j) { SN = fmaf(lam, SN, a[j] * vv[j]); SD = fmaf(lam, SD, a[j]); }
    float BN = 0.f, BD = 0.f;
    #pragma unroll
    for (int j = 15; j >= 0; --j) { BN = fmaf(lam, BN, a[j] * vv[j]); BD = fmaf(lam, BD, a[j]); }

    __shared__ float sN[2][256], sD[2][256];

    sN[0][tid] = SN; sD[0][tid] = SD;
    __syncthreads();
    int src = 0;
    float f = lam16;
    for (int o = 1; o < 256; o <<= 1) {
        float nN = sN[src][tid], nD = sD[src][tid];
        if (tid >= o) { nN = fmaf(f, sN[src][tid - o], nN); nD = fmaf(f, sD[src][tid - o], nD); }
        sN[src ^ 1][tid] = nN; sD[src ^ 1][tid] = nD;
        __syncthreads();
        src ^= 1; f = f * f;
    }
    const float CfN = (tid > 0) ? sN[src][tid - 1] : 0.f;
    const float CfD = (tid > 0) ? sD[src][tid - 1] : 0.f;
    __syncthreads();

    sN[0][tid] = BN; sD[0][tid] = BD;
    __syncthreads();
    src = 0; f = lam16;
    for (int o = 1; o < 256; o <<= 1) {
        float nN = sN[src][tid], nD = sD[src][tid];
        if (tid + o < 256) { nN = fmaf(f, sN[src][tid + o], nN); nD = fmaf(f, sD[src][tid + o], nD); }
        sN[src ^ 1][tid] = nN; sD[src ^ 1][tid] = nD;
        __syncthreads();
        src ^= 1; f = f * f;
    }
    const float CbN = (tid < 255) ? sN[src][tid + 1] : 0.f;
    const float CbD = (tid < 255) ? sD[src][tid + 1] : 0.f;

    float fN[16], fD[16];
    float cN = CfN, cD = CfD;
    #pragma unroll
    for (int j = 0; j < 16; ++j) {
        fN[j] = cN; fD[j] = cD;
        cN = fmaf(lam, cN, a[j] * vv[j]);
        cD = fmaf(lam, cD, a[j]);
    }

    float sl[16];
    #pragma unroll
    for (int j = 0; j < 16; j += 4) *(float4*)&sl[j] = *(const float4*)&sr[t0 + j];

    u16 oh[16], ol[16];
    float bN = CbN, bD = CbD;
    #pragma unroll
    for (int j = 15; j >= 0; --j) {
        const float es = expf(u + kk[j] - m);
        const float num = fN[j] + bN + es * vv[j];
        const float den = fD[j] + bD + es;
        const float y = num / den;
        const float sig = 1.0f / (1.0f + expf(-sl[j]));
        split_bf16(sig * y, oh[j], ol[j]);
        bN = fmaf(lam, bN, a[j] * vv[j]);
        bD = fmaf(lam, bD, a[j]);
    }

    u32 ph[8], pl[8];
    #pragma unroll
    for (int j = 0; j < 8; ++j) {
        ph[j] = (u32)oh[2 * j] | ((u32)oh[2 * j + 1] << 16);
        pl[j] = (u32)ol[2 * j] | ((u32)ol[2 * j + 1] << 16);
    }
    *(uint4*)&yh[t0]     = make_uint4(ph[0], ph[1], ph[2], ph[3]);
    *(uint4*)&yh[t0 + 8] = make_uint4(ph[4], ph[5], ph[6], ph[7]);
    *(uint4*)&yl[t0]     = make_uint4(pl[0], pl[1], pl[2], pl[3]);
    *(uint4*)&yl[t0 + 8] = make_uint4(pl[4], pl[5], pl[6], pl[7]);
}

// ---------------------------------------------------------------------------
extern "C" void kernel_launch(void* const* d_in, const int* in_sizes, int n_in,
                              void* d_out, int out_size, void* d_ws, size_t ws_size,
                              hipStream_t stream) {
    const float* x        = (const float*)d_in[0];
    const float* w_key    = (const float*)d_in[1];
    const float* w_value  = (const float*)d_in[2];
    const float* w_recept = (const float*)d_in[3];
    const float* w_out    = (const float*)d_in[4];
    const float* decay    = (const float*)d_in[5];
    const float* boost    = (const float*)d_in[6];
    const float* alpha    = (const float*)d_in[7];
    const float* dw1      = (const float*)d_in[8];
    const float* dw3      = (const float*)d_in[9];
    const float* dw5      = (const float*)d_in[10];

    const size_t S = (size_t)Bn * Cn * Tn;   // 6291456 elements
    u16* R0 = (u16*)d_ws;                    // 2S u16 each region
    u16* R1 = R0 + 2 * S;
    u16* R2 = R1 + 2 * S;
    u16* whp = R2 + 2 * S;                   // stacked weights hi (4*36864)
    u16* wlp = whp + 4 * 36864;

    u16* xs_hi = R0;        u16* xs_lo = R0 + S;      // omni out / transpose in
    u16* Xt_hi = R1;        u16* Xt_lo = R1 + S;      // transpose out / proj in
    float* kb  = (float*)R0;                          // proj out (xs dead)
    float* vb  = (float*)R2;
    float* srl = (float*)d_out;                       // scratch until final GEMM
    u16* y_hi  = R1;        u16* y_lo  = R1 + S;      // wkv out (Xt dead)
    u16* Yt_hi = R2;        u16* Yt_lo = R2 + S;      // y-transpose out (vb dead)
    float* out = (float*)d_out;

    // blocks 1536..1727 also perform the weight hi/lo split
    omni_kernel<<<dim3(1536 + 192), 256, 0, stream>>>(x, alpha, dw1, dw3, dw5,
                                                      w_key, w_value, w_recept, w_out,
                                                      xs_hi, xs_lo, whp, wlp);

    transpose_kernel<<<dim3(32, 6, 8), 256, 0, stream>>>(xs_hi, xs_lo, Xt_hi, Xt_lo);

    gemm_mfma<3><<<dim3(32, 3, 8), 256, 0, stream>>>(whp, wlp, Xt_hi, Xt_lo, kb, vb, srl, 0);

    wkv_kernel<<<dim3(Bn * Cn), 256, 0, stream>>>(kb, vb, srl, decay, boost, y_hi, y_lo);

    transpose_kernel<<<dim3(32, 6, 8), 256, 0, stream>>>(y_hi, y_lo, Yt_hi, Yt_lo);

    gemm_mfma<1><<<dim3(32, 3, 8), 256, 0, stream>>>(whp, wlp, Yt_hi, Yt_lo, out, nullptr, nullptr, 576);
}

// Round 10
// 107.903 us; speedup vs baseline: 1.3273x; 1.1295x over previous
//
#include <hip/hip_runtime.h>
#include <math.h>

#define Cn 192
#define Bn 8
#define Tn 4096
#define HW 64

typedef unsigned short u16;
typedef unsigned int u32;
typedef __attribute__((ext_vector_type(8))) __bf16 bf16x8;
typedef __attribute__((ext_vector_type(16))) float f32x16;

__device__ __forceinline__ void gload16(const void* g, void* l) {
    __builtin_amdgcn_global_load_lds(
        (const __attribute__((address_space(1))) void*)g,
        (__attribute__((address_space(3))) void*)l, 16, 0, 0);
}

__device__ __forceinline__ void split_bf16(float x, u16 &h, u16 &l) {
    u32 u = __float_as_uint(x);
    u32 uh = (u + 0x7FFFu + ((u >> 16) & 1u)) & 0xFFFF0000u;
    h = (u16)(uh >> 16);
    float r = x - __uint_as_float(uh);
    u32 ur = __float_as_uint(r);
    l = (u16)((ur + 0x7FFFu + ((ur >> 16) & 1u)) >> 16);
}

// ---------------------------------------------------------------------------
// Kernel 1: omni_shift (fused 25-tap depthwise conv) -> split bf16 hi/lo out.
// Blocks >= 1536 perform the weight hi/lo split (fused to save a dispatch).
// ---------------------------------------------------------------------------
__global__ __launch_bounds__(256) void omni_kernel(const float* __restrict__ x,
                                                   const float* __restrict__ alpha,
                                                   const float* __restrict__ dw1,
                                                   const float* __restrict__ dw3,
                                                   const float* __restrict__ dw5,
                                                   const float* __restrict__ Wk,
                                                   const float* __restrict__ Wv,
                                                   const float* __restrict__ Wr,
                                                   const float* __restrict__ Wo,
                                                   u16* __restrict__ xhi,
                                                   u16* __restrict__ xlo,
                                                   u16* __restrict__ wh,
                                                   u16* __restrict__ wl) {
    const int tid = threadIdx.x;
    if (blockIdx.x >= 1536) {
        const int base = (blockIdx.x - 1536) * 768;
        #pragma unroll
        for (int jj = 0; jj < 3; ++jj) {
            int idx = base + jj * 256 + tid;
            int mat = idx / 36864;
            int off = idx - mat * 36864;
            const float* src = (mat == 0) ? Wk : (mat == 1) ? Wv : (mat == 2) ? Wr : Wo;
            u16 h, l;
            split_bf16(src[off], h, l);
            wh[idx] = h;
            wl[idx] = l;
        }
        return;
    }

    const int plane = blockIdx.x;          // b*C + c
    const int c = plane % Cn;
    const float* xin = x + (size_t)plane * Tn;
    u16* oh = xhi + (size_t)plane * Tn;
    u16* ol = xlo + (size_t)plane * Tn;

    __shared__ float tile[68 * 68];
    __shared__ float wk[25];

    if (tid == 0) {
        const float a0 = alpha[0], a1 = alpha[1], a2 = alpha[2], a3 = alpha[3];
        #pragma unroll
        for (int j = 0; j < 25; ++j) wk[j] = a3 * dw5[c * 25 + j];
        #pragma unroll
        for (int dy = 0; dy < 3; ++dy)
            #pragma unroll
            for (int dx = 0; dx < 3; ++dx)
                wk[(dy + 1) * 5 + (dx + 1)] += a2 * dw3[c * 9 + dy * 3 + dx];
        wk[12] += a1 * dw1[c] + a0;
    }
    for (int i = tid; i < 68 * 68; i += 256) {
        int r = i / 68, cc = i - r * 68;
        int gy = r - 2, gx = cc - 2;
        float v = 0.f;
        if (gy >= 0 && gy < HW && gx >= 0 && gx < HW) v = xin[gy * HW + gx];
        tile[i] = v;
    }
    __syncthreads();

    const int py = tid >> 3;          // 0..31
    const int px0 = (tid & 7) << 3;   // 0,8,..,56

    #pragma unroll
    for (int half = 0; half < 2; ++half) {
        const int y = py + half * 32;
        float row[5][12];
        #pragma unroll
        for (int dy = 0; dy < 5; ++dy) {
            const float4* rp = (const float4*)&tile[(y + dy) * 68 + px0];
            float4 r0 = rp[0], r1 = rp[1], r2 = rp[2];
            row[dy][0] = r0.x; row[dy][1] = r0.y; row[dy][2]  = r0.z; row[dy][3]  = r0.w;
            row[dy][4] = r1.x; row[dy][5] = r1.y; row[dy][6]  = r1.z; row[dy][7]  = r1.w;
            row[dy][8] = r2.x; row[dy][9] = r2.y; row[dy][10] = r2.z; row[dy][11] = r2.w;
        }
        u32 ph[4], pl[4];
        #pragma unroll
        for (int jj = 0; jj < 8; ++jj) {
            float acc = 0.f;
            #pragma unroll
            for (int dy = 0; dy < 5; ++dy)
                #pragma unroll
                for (int dx = 0; dx < 5; ++dx)
                    acc = fmaf(row[dy][jj + dx], wk[dy * 5 + dx], acc);
            u16 h, l2;
            split_bf16(acc, h, l2);
            if (jj & 1) { ph[jj >> 1] |= ((u32)h) << 16; pl[jj >> 1] |= ((u32)l2) << 16; }
            else        { ph[jj >> 1] = h;               pl[jj >> 1] = l2; }
        }
        *(uint4*)&oh[y * 64 + px0] = make_uint4(ph[0], ph[1], ph[2], ph[3]);
        *(uint4*)&ol[y * 64 + px0] = make_uint4(pl[0], pl[1], pl[2], pl[3]);
    }
}

// ---------------------------------------------------------------------------
// Kernel 2: fused k/v/sr projection GEMM reading xs directly from [b][c][t].
// A (3x64 weight rows) via gload_lds with XOR-swizzled source (R9-verified).
// B tile transposed in-kernel: coalesced global b128 row loads -> regs ->
// contiguous-across-lanes ds_write_b32 into [t][36] LDS (row stride 72 B
// == 2 mod 32 dwords -> b64 frag reads are 2 lanes/bank, free).
// B regs prefetched one K-step ahead. LDS 43 KB -> 3 blocks/CU.
// ---------------------------------------------------------------------------
__global__ __launch_bounds__(256) void gemm_proj(const u16* __restrict__ wh,
                                                 const u16* __restrict__ wl,
                                                 const u16* __restrict__ Xh,
                                                 const u16* __restrict__ Xl,
                                                 float* __restrict__ O0,
                                                 float* __restrict__ O1,
                                                 float* __restrict__ O2) {
    __shared__ u16 Ah_[3 * 64 * 32], Al_[3 * 64 * 32];
    __shared__ u16 Bh_[128 * 36], Bl_[128 * 36];

    const int tid  = threadIdx.x;
    const int l    = tid & 63;
    const int wave = tid >> 6;
    const int wm   = wave >> 1, wn = wave & 1;
    const int m0   = blockIdx.y * 64;
    const int t0   = blockIdx.x * 128;
    const size_t xb = (size_t)blockIdx.z * Cn * Tn;
    const int cpair = tid & 15;         // c-pair 0..15 (c = 2*cpair, 2*cpair+1)
    const int toct  = tid >> 4;         // t-oct 0..15

    f32x16 acc[3][2];
    #pragma unroll
    for (int m = 0; m < 3; ++m)
        #pragma unroll
        for (int nf = 0; nf < 2; ++nf)
            #pragma unroll
            for (int r = 0; r < 16; ++r) acc[m][nf][r] = 0.f;

    uint4 rh0, rh1, rl0, rl1;           // B reg-stage (one K-step)

    auto loadB = [&](int k0) {
        size_t g = xb + (size_t)(k0 + 2 * cpair) * Tn + t0 + toct * 8;
        rh0 = *(const uint4*)&Xh[g];
        rh1 = *(const uint4*)&Xh[g + Tn];
        rl0 = *(const uint4*)&Xl[g];
        rl1 = *(const uint4*)&Xl[g + Tn];
    };
    auto writeB = [&]() {
        const u32 h0[4] = {rh0.x, rh0.y, rh0.z, rh0.w};
        const u32 h1[4] = {rh1.x, rh1.y, rh1.z, rh1.w};
        const u32 l0[4] = {rl0.x, rl0.y, rl0.z, rl0.w};
        const u32 l1[4] = {rl1.x, rl1.y, rl1.z, rl1.w};
        #pragma unroll
        for (int j = 0; j < 8; ++j) {
            int t = toct * 8 + j;
            int sh = 16 * (j & 1);
            u32 a = (h0[j >> 1] >> sh) & 0xFFFFu;
            u32 b = (h1[j >> 1] >> sh) & 0xFFFFu;
            *(u32*)&Bh_[t * 36 + 2 * cpair] = a | (b << 16);
            u32 c = (l0[j >> 1] >> sh) & 0xFFFFu;
            u32 d = (l1[j >> 1] >> sh) & 0xFFFFu;
            *(u32*)&Bl_[t * 36 + 2 * cpair] = c | (d << 16);
        }
    };
    auto stageA = [&](int k0) {
        #pragma unroll
        for (int i = 0; i < 3; ++i) {
            int idx = i * 256 + tid;
            int row = idx >> 2;
            int cb  = (idx & 3) ^ ((row >> 1) & 3);
            int grow = (row >> 6) * 192 + m0 + (row & 63);
            gload16(wh + (size_t)grow * Cn + k0 + cb * 8, Ah_ + idx * 8);
            gload16(wl + (size_t)grow * Cn + k0 + cb * 8, Al_ + idx * 8);
        }
    };
    auto compute = [&]() {
        #pragma unroll
        for (int kh = 0; kh < 2; ++kh) {
            const int cbb = kh * 2 + (l >> 5);
            bf16x8 ah[3], al[3];
            #pragma unroll
            for (int m = 0; m < 3; ++m) {
                int r = m * 64 + wm * 32 + (l & 31);
                int off = r * 32 + ((cbb ^ ((r >> 1) & 3)) << 3);
                ah[m] = *(const bf16x8*)&Ah_[off];
                al[m] = *(const bf16x8*)&Al_[off];
            }
            #pragma unroll
            for (int nf = 0; nf < 2; ++nf) {
                int t = wn * 64 + nf * 32 + (l & 31);
                int o = t * 36 + cbb * 8;
                union { uint2 q[2]; bf16x8 v; } th, tl2;
                th.q[0]  = *(const uint2*)&Bh_[o];
                th.q[1]  = *(const uint2*)&Bh_[o + 4];
                tl2.q[0] = *(const uint2*)&Bl_[o];
                tl2.q[1] = *(const uint2*)&Bl_[o + 4];
                #pragma unroll
                for (int m = 0; m < 3; ++m) {
                    acc[m][nf] = __builtin_amdgcn_mfma_f32_32x32x16_bf16(ah[m], th.v,  acc[m][nf], 0, 0, 0);
                    acc[m][nf] = __builtin_amdgcn_mfma_f32_32x32x16_bf16(ah[m], tl2.v, acc[m][nf], 0, 0, 0);
                    acc[m][nf] = __builtin_amdgcn_mfma_f32_32x32x16_bf16(al[m], th.v,  acc[m][nf], 0, 0, 0);
                }
            }
        }
    };

    loadB(0);
    stageA(0);
    writeB();                           // waits vmcnt on B regs
    __syncthreads();                    // drains A gloads + B writes visible
    loadB(32);
    for (int ks = 0; ks < 6; ++ks) {
        compute();
        if (ks < 5) {
            __syncthreads();            // readers done with LDS
            writeB();                   // B regs from prefetch
            stageA((ks + 1) * 32);
            __syncthreads();            // A drained + B writes visible
            if (ks < 4) loadB((ks + 2) * 32);
        }
    }

    float* Os[3] = {O0, O1, O2};
    #pragma unroll
    for (int m = 0; m < 3; ++m) {
        float* O = Os[m] + (size_t)blockIdx.z * Cn * Tn;
        #pragma unroll
        for (int nf = 0; nf < 2; ++nf) {
            int col = t0 + wn * 64 + nf * 32 + (l & 31);
            #pragma unroll
            for (int r = 0; r < 16; ++r) {
                int row = m0 + wm * 32 + (r & 3) + 8 * (r >> 2) + 4 * (l >> 5);
                O[(size_t)row * Tn + col] = acc[m][nf][r];
            }
        }
    }
}

// ---------------------------------------------------------------------------
// Kernel 3: wkv_stats — per-(b,d) row, per-16-chunk exclusive fwd/bwd states.
// No max-subtraction (f32 range analysis: |k| <~ 15 -> sums <= ~1e11, safe;
// numerator/denominator scale cancels so y is unchanged up to rounding).
// ---------------------------------------------------------------------------
__global__ __launch_bounds__(256) void wkv_stats(const float* __restrict__ kg,
                                                 const float* __restrict__ vg,
                                                 const float* __restrict__ decay,
                                                 float4* __restrict__ states) {
    const int row = blockIdx.x;       // b*C + d
    const int d = row % Cn;
    const float* kr = kg + (size_t)row * Tn;
    const float* vr = vg + (size_t)row * Tn;

    const int tid = threadIdx.x;
    const int t0 = tid * 16;

    float kk[16], vv[16];
    #pragma unroll
    for (int j = 0; j < 16; j += 4) {
        *(float4*)&kk[j] = *(const float4*)&kr[t0 + j];
        *(float4*)&vv[j] = *(const float4*)&vr[t0 + j];
    }

    const float ww = decay[d] * (1.0f / (float)Tn);
    const float lam = expf(-ww);
    const float lam16 = expf(-16.0f * ww);

    float a[16];
    #pragma unroll
    for (int j = 0; j < 16; ++j) a[j] = expf(kk[j]);

    float SN = 0.f, SD = 0.f;
    #pragma unroll
    for (int j = 0; j < 16; ++j) { SN = fmaf(lam, SN, a[j] * vv[j]); SD = fmaf(lam, SD, a[j]); }
    float BN = 0.f, BD = 0.f;
    #pragma unroll
    for (int j = 15; j >= 0; --j) { BN = fmaf(lam, BN, a[j] * vv[j]); BD = fmaf(lam, BD, a[j]); }

    __shared__ float sN[2][256], sD[2][256];

    sN[0][tid] = SN; sD[0][tid] = SD;
    __syncthreads();
    int src = 0;
    float f = lam16;
    for (int o = 1; o < 256; o <<= 1) {
        float nN = sN[src][tid], nD = sD[src][tid];
        if (tid >= o) { nN = fmaf(f, sN[src][tid - o], nN); nD = fmaf(f, sD[src][tid - o], nD); }
        sN[src ^ 1][tid] = nN; sD[src ^ 1][tid] = nD;
        __syncthreads();
        src ^= 1; f = f * f;
    }
    const float CfN = (tid > 0) ? sN[src][tid - 1] : 0.f;
    const float CfD = (tid > 0) ? sD[src][tid - 1] : 0.f;
    __syncthreads();

    sN[0][tid] = BN; sD[0][tid] = BD;
    __syncthreads();
    src = 0; f = lam16;
    for (int o = 1; o < 256; o <<= 1) {
        float nN = sN[src][tid], nD = sD[src][tid];
        if (tid + o < 256) { nN = fmaf(f, sN[src][tid + o], nN); nD = fmaf(f, sD[src][tid + o], nD); }
        sN[src ^ 1][tid] = nN; sD[src ^ 1][tid] = nD;
        __syncthreads();
        src ^= 1; f = f * f;
    }
    const float CbN = (tid < 255) ? sN[src][tid + 1] : 0.f;
    const float CbD = (tid < 255) ? sD[src][tid + 1] : 0.f;

    const int b = row / Cn;
    states[((size_t)(b * 256 + tid)) * Cn + d] = make_float4(CfN, CfD, CbN, CbD);
}

// ---------------------------------------------------------------------------
// Kernel 4: wkv_out — block (b, t-tile 128) x all 192 d. Combines chunk
// states -> y = sigmoid(sr) * wkv, writes y^T hi/lo straight into LDS
// [128 t][196] (contiguous-lane u16 writes, bank-clean), then runs the
// out-projection GEMM with B already resident and writes the final output.
// 256 blocks (1/CU), 512 threads, LDS ~125 KB.
// ---------------------------------------------------------------------------
__global__ __launch_bounds__(512) void wkv_out(const float* __restrict__ kb,
                                               const float* __restrict__ vb,
                                               const float* __restrict__ srl,
                                               const float4* __restrict__ states,
                                               const float* __restrict__ decay,
                                               const float* __restrict__ boost,
                                               const u16* __restrict__ wh,
                                               const u16* __restrict__ wl,
                                               float* __restrict__ out) {
    __shared__ u16 Yh_[128 * 196], Yl_[128 * 196];
    __shared__ u16 Ah_[192 * 32], Al_[192 * 32];

    const int tid = threadIdx.x;
    const int b = blockIdx.y;
    const int t0 = blockIdx.x * 128;

    // ---- combine phase: 1536 (d, chunk) tasks over 512 threads ----
    for (int pass = 0; pass < 3; ++pass) {
        const int task = pass * 512 + tid;
        const int d  = task % Cn;
        const int ch = task / Cn;          // 0..7
        const size_t rbase = ((size_t)b * Cn + d) * Tn + t0 + ch * 16;
        const float4 st = states[((size_t)(b * 256 + (t0 >> 4) + ch)) * Cn + d];
        const float ww = decay[d] * (1.0f / (float)Tn);
        const float lam = expf(-ww);
        const float u = boost[d] * (1.0f / (float)Tn);

        float kk[16], vv[16], sl[16];
        #pragma unroll
        for (int j = 0; j < 16; j += 4) {
            *(float4*)&kk[j] = *(const float4*)&kb[rbase + j];
            *(float4*)&vv[j] = *(const float4*)&vb[rbase + j];
            *(float4*)&sl[j] = *(const float4*)&srl[rbase + j];
        }
        float a[16];
        #pragma unroll
        for (int j = 0; j < 16; ++j) a[j] = expf(kk[j]);

        float fN[16], fD[16];
        float cN = st.x, cD = st.y;
        #pragma unroll
        for (int j = 0; j < 16; ++j) {
            fN[j] = cN; fD[j] = cD;
            cN = fmaf(lam, cN, a[j] * vv[j]);
            cD = fmaf(lam, cD, a[j]);
        }
        float bN = st.z, bD = st.w;
        #pragma unroll
        for (int j = 15; j >= 0; --j) {
            const float es = expf(u + kk[j]);
            const float y = (fN[j] + bN + es * vv[j]) / (fD[j] + bD + es);
            const float sig = 1.0f / (1.0f + expf(-sl[j]));
            u16 h, l2;
            split_bf16(sig * y, h, l2);
            const int t = ch * 16 + j;
            Yh_[t * 196 + d] = h;
            Yl_[t * 196 + d] = l2;
            bN = fmaf(lam, bN, a[j] * vv[j]);
            bD = fmaf(lam, bD, a[j]);
        }
    }
    __syncthreads();

    // ---- out-projection GEMM: M=192 (w_out rows), N=128 (t), K=192 (d) ----
    const int l = tid & 63;
    const int wave = tid >> 6;
    const int wm = wave >> 2;           // 0..1  (96 M-rows each)
    const int wn = wave & 3;            // 0..3  (32 t-cols each)

    f32x16 acc[3];
    #pragma unroll
    for (int mf = 0; mf < 3; ++mf)
        #pragma unroll
        for (int r = 0; r < 16; ++r) acc[mf][r] = 0.f;

    for (int ks = 0; ks < 6; ++ks) {
        // stage A = w_out slice (rows 576..767 of stacked weights), 192x32
        {
            int idx = tid;
            int row = idx >> 2;
            int cb = (idx & 3) ^ ((row >> 1) & 3);
            gload16(wh + (size_t)(576 + row) * Cn + ks * 32 + cb * 8, Ah_ + idx * 8);
            gload16(wl + (size_t)(576 + row) * Cn + ks * 32 + cb * 8, Al_ + idx * 8);
            if (tid < 256) {
                idx = 512 + tid;
                row = idx >> 2;
                cb = (idx & 3) ^ ((row >> 1) & 3);
                gload16(wh + (size_t)(576 + row) * Cn + ks * 32 + cb * 8, Ah_ + idx * 8);
                gload16(wl + (size_t)(576 + row) * Cn + ks * 32 + cb * 8, Al_ + idx * 8);
            }
        }
        __syncthreads();                 // A drained, safe to read
        #pragma unroll
        for (int kh = 0; kh < 2; ++kh) {
            const int cbb = kh * 2 + (l >> 5);
            bf16x8 ah[3], al[3];
            #pragma unroll
            for (int mf = 0; mf < 3; ++mf) {
                int r = wm * 96 + mf * 32 + (l & 31);
                int off = r * 32 + ((cbb ^ ((r >> 1) & 3)) << 3);
                ah[mf] = *(const bf16x8*)&Ah_[off];
                al[mf] = *(const bf16x8*)&Al_[off];
            }
            const int t = wn * 32 + (l & 31);
            const int o = t * 196 + ks * 32 + cbb * 8;
            union { uint2 q[2]; bf16x8 v; } bh, bl;
            bh.q[0] = *(const uint2*)&Yh_[o];
            bh.q[1] = *(const uint2*)&Yh_[o + 4];
            bl.q[0] = *(const uint2*)&Yl_[o];
            bl.q[1] = *(const uint2*)&Yl_[o + 4];
            #pragma unroll
            for (int mf = 0; mf < 3; ++mf) {
                acc[mf] = __builtin_amdgcn_mfma_f32_32x32x16_bf16(ah[mf], bh.v, acc[mf], 0, 0, 0);
                acc[mf] = __builtin_amdgcn_mfma_f32_32x32x16_bf16(ah[mf], bl.v, acc[mf], 0, 0, 0);
                acc[mf] = __builtin_amdgcn_mfma_f32_32x32x16_bf16(al[mf], bh.v, acc[mf], 0, 0, 0);
            }
        }
        __syncthreads();                 // readers done before next A overwrite
    }

    #pragma unroll
    for (int mf = 0; mf < 3; ++mf) {
        const int col = t0 + wn * 32 + (l & 31);
        #pragma unroll
        for (int r = 0; r < 16; ++r) {
            int row = wm * 96 + mf * 32 + (r & 3) + 8 * (r >> 2) + 4 * (l >> 5);
            out[((size_t)b * Cn + row) * Tn + col] = acc[mf][r];
        }
    }
}

// ---------------------------------------------------------------------------
extern "C" void kernel_launch(void* const* d_in, const int* in_sizes, int n_in,
                              void* d_out, int out_size, void* d_ws, size_t ws_size,
                              hipStream_t stream) {
    const float* x        = (const float*)d_in[0];
    const float* w_key    = (const float*)d_in[1];
    const float* w_value  = (const float*)d_in[2];
    const float* w_recept = (const float*)d_in[3];
    const float* w_out    = (const float*)d_in[4];
    const float* decay    = (const float*)d_in[5];
    const float* boost    = (const float*)d_in[6];
    const float* alpha    = (const float*)d_in[7];
    const float* dw1      = (const float*)d_in[8];
    const float* dw3      = (const float*)d_in[9];
    const float* dw5      = (const float*)d_in[10];

    const size_t S = (size_t)Bn * Cn * Tn;   // 6291456 elements
    u16* R0 = (u16*)d_ws;                    // 2S u16 each region
    u16* R1 = R0 + 2 * S;
    u16* R2 = R1 + 2 * S;
    u16* whp = R2 + 2 * S;                   // stacked weights hi (4*36864)
    u16* wlp = whp + 4 * 36864;

    u16* xs_hi = R0;        u16* xs_lo = R0 + S;      // omni out / proj in
    float* kb  = (float*)R1;                          // proj out
    float* vb  = (float*)R2;
    float* srl = (float*)d_out;                       // scratch until wkv_out
    float4* states = (float4*)R0;                     // after xs dead (6.3 MB)
    float* out = (float*)d_out;

    // blocks 1536..1727 also perform the weight hi/lo split
    omni_kernel<<<dim3(1536 + 192), 256, 0, stream>>>(x, alpha, dw1, dw3, dw5,
                                                      w_key, w_value, w_recept, w_out,
                                                      xs_hi, xs_lo, whp, wlp);

    gemm_proj<<<dim3(32, 3, 8), 256, 0, stream>>>(whp, wlp, xs_hi, xs_lo, kb, vb, srl);

    wkv_stats<<<dim3(Bn * Cn), 256, 0, stream>>>(kb, vb, decay, states);

    wkv_out<<<dim3(32, 8), 512, 0, stream>>>(kb, vb, srl, states, decay, boost,
                                             whp, wlp, out);
}